// Round 1
// baseline (22417.450 us; speedup 1.0000x reference)
//
#include <hip/hip_runtime.h>
#include <cstdint>
#include <cmath>

// RNG variant: 1 = partitionable (foldlike split, bits = r0^r1)  [modern JAX default]
//              2 = original    (iota split, concat bits)
//              3 = partitionable, bits = r1 (truncate-64-to-32 interpretation)
#define RNG_VARIANT 1

#define NROWS 4096
#define HIDN 512
#define G4 2048
#define VOC 32
#define TSTEPS 64
#define PAD_TOK 0
#define BOS_TOK 1
#define EOS_TOK 2

// ---------------- threefry2x32 (JAX-compatible, 20 rounds) ----------------
__host__ __device__ inline void tf2x32(unsigned k0, unsigned k1, unsigned x0, unsigned x1,
                                       unsigned& o0, unsigned& o1) {
  unsigned ks0 = k0, ks1 = k1, ks2 = k0 ^ k1 ^ 0x1BD11BDAu;
  unsigned X0 = x0 + ks0, X1 = x1 + ks1;
  const unsigned R[5][4] = {{13,15,26,6},{17,29,16,24},{13,15,26,6},{17,29,16,24},{13,15,26,6}};
  unsigned inj0[5], inj1[5];
  inj0[0] = ks1; inj1[0] = ks2;
  inj0[1] = ks2; inj1[1] = ks0;
  inj0[2] = ks0; inj1[2] = ks1;
  inj0[3] = ks1; inj1[3] = ks2;
  inj0[4] = ks2; inj1[4] = ks0;
#pragma unroll
  for (int i = 0; i < 5; ++i) {
#pragma unroll
    for (int j = 0; j < 4; ++j) {
      X0 += X1;
      unsigned r = R[i][j];
      X1 = (X1 << r) | (X1 >> (32 - r));
      X1 ^= X0;
    }
    X0 += inj0[i];
    X1 += inj1[i] + (unsigned)(i + 1);
  }
  o0 = X0; o1 = X1;
}

// ---------------- fp32 NT GEMM: C[4096][2048] = sum_parts A_p @ B_p^T ----------------
// A_p: 4096x512 row-major (ld=512), B_p: 2048x512 row-major (ld=512)
#define BM 128
#define BN 128
#define BK 32
#define LDP 132  // +4 pad: 4-way bank conflict on transposed LDS writes, aligned b128 reads

__global__ __launch_bounds__(256) void lstm_gemm(
    const float* __restrict__ A0, const float* __restrict__ B0,
    const float* __restrict__ A1, const float* __restrict__ B1,
    int nparts, float* __restrict__ C)
{
  __shared__ float As[BK][LDP];
  __shared__ float Bs[BK][LDP];
  const int tid = threadIdx.x;
  const int tx = tid & 15, ty = tid >> 4;
  const int m0 = blockIdx.y * BM, n0 = blockIdx.x * BN;
  const int lrow = tid >> 3;          // 0..31
  const int lcol = (tid & 7) << 2;    // 0,4,...,28
  float acc[8][8];
#pragma unroll
  for (int i = 0; i < 8; ++i)
#pragma unroll
    for (int j = 0; j < 8; ++j) acc[i][j] = 0.f;

  for (int part = 0; part < nparts; ++part) {
    const float* __restrict__ A = part ? A1 : A0;
    const float* __restrict__ B = part ? B1 : B0;
    for (int kt = 0; kt < HIDN / BK; ++kt) {
      const int kb = kt * BK;
#pragma unroll
      for (int p = 0; p < 4; ++p) {
        const int r = lrow + 32 * p;
        float4 va = *reinterpret_cast<const float4*>(A + (size_t)(m0 + r) * HIDN + kb + lcol);
        float4 vb = *reinterpret_cast<const float4*>(B + (size_t)(n0 + r) * HIDN + kb + lcol);
        As[lcol + 0][r] = va.x; As[lcol + 1][r] = va.y; As[lcol + 2][r] = va.z; As[lcol + 3][r] = va.w;
        Bs[lcol + 0][r] = vb.x; Bs[lcol + 1][r] = vb.y; Bs[lcol + 2][r] = vb.z; Bs[lcol + 3][r] = vb.w;
      }
      __syncthreads();
#pragma unroll
      for (int k = 0; k < BK; ++k) {
        float a[8], b[8];
        *reinterpret_cast<float4*>(&a[0]) = *reinterpret_cast<const float4*>(&As[k][ty * 8]);
        *reinterpret_cast<float4*>(&a[4]) = *reinterpret_cast<const float4*>(&As[k][ty * 8 + 4]);
        *reinterpret_cast<float4*>(&b[0]) = *reinterpret_cast<const float4*>(&Bs[k][tx * 8]);
        *reinterpret_cast<float4*>(&b[4]) = *reinterpret_cast<const float4*>(&Bs[k][tx * 8 + 4]);
#pragma unroll
        for (int i = 0; i < 8; ++i)
#pragma unroll
          for (int j = 0; j < 8; ++j)
            acc[i][j] = fmaf(a[i], b[j], acc[i][j]);
      }
      __syncthreads();
    }
  }
#pragma unroll
  for (int i = 0; i < 8; ++i) {
    float4 v0 = make_float4(acc[i][0], acc[i][1], acc[i][2], acc[i][3]);
    float4 v1 = make_float4(acc[i][4], acc[i][5], acc[i][6], acc[i][7]);
    float* cp = C + (size_t)(m0 + ty * 8 + i) * G4 + n0 + tx * 8;
    *reinterpret_cast<float4*>(cp) = v0;
    *reinterpret_cast<float4*>(cp + 4) = v1;
  }
}

// ---------------- LSTM gate nonlinearity + state update ----------------
// extra = EW0 (32 rows, indexed by tok) for layer0, or bias1 (1 row, tok==nullptr) for layer1
__global__ void lstm_act(const float* __restrict__ gates,
                         const float* __restrict__ extra,
                         const int* __restrict__ tok,
                         float* __restrict__ h, float* __restrict__ c)
{
  const int n = blockIdx.x;
  const int j = blockIdx.y * 256 + threadIdx.x;   // 0..511
  const float* ex = extra + (tok ? (size_t)tok[n] * G4 : 0);
  const size_t base = (size_t)n * G4;
  float gi = gates[base + j]        + ex[j];
  float gf = gates[base + j + 512]  + ex[j + 512];
  float gg = gates[base + j + 1024] + ex[j + 1024];
  float go = gates[base + j + 1536] + ex[j + 1536];
  float si = 1.f / (1.f + expf(-gi));
  float sf = 1.f / (1.f + expf(-gf));
  float tg = tanhf(gg);
  float so = 1.f / (1.f + expf(-go));
  const size_t hi = (size_t)n * HIDN + j;
  float cn = sf * c[hi] + si * tg;
  c[hi] = cn;
  h[hi] = so * tanhf(cn);
}

// ---------------- precompute EW0[v][j] = (emb[v] @ W_ih0^T)[j] + b_ih0[j] + b_hh0[j] ----------------
__global__ void build_ew0(const float* __restrict__ emb, const float* __restrict__ W_ih0,
                          const float* __restrict__ b_ih0, const float* __restrict__ b_hh0,
                          float* __restrict__ EW0)
{
  int idx = blockIdx.x * 256 + threadIdx.x;  // 32*2048
  int vv = idx >> 11, j = idx & 2047;
  float s = b_ih0[j] + b_hh0[j];
#pragma unroll
  for (int e = 0; e < 32; ++e)
    s = fmaf(emb[vv * 32 + e], W_ih0[(size_t)j * 32 + e], s);
  EW0[idx] = s;
}

__global__ void add_bias(const float* __restrict__ a, const float* __restrict__ b,
                         float* __restrict__ o) {
  int j = blockIdx.x * 256 + threadIdx.x;
  if (j < G4) o[j] = a[j] + b[j];
}

__global__ void init_state(const int* __restrict__ prevs, int* __restrict__ tok,
                           int* __restrict__ is_end, int* __restrict__ lengths,
                           int* __restrict__ out)
{
  int n = blockIdx.x * 256 + threadIdx.x;
  if (n < NROWS) {
    int p = prevs[n];
    tok[n] = p;
    is_end[n] = (p == EOS_TOK) ? 1 : 0;
    lengths[n] = 0;
    out[(size_t)n * (TSTEPS + 1)] = p;
  }
}

// ---------------- logits + gumbel + argmax + token/state update (1 wave / row) ----------------
__global__ __launch_bounds__(64) void sample_step(
    const float* __restrict__ h1, const float* __restrict__ W_out,
    const float* __restrict__ b_out,
    int* __restrict__ tok, int* __restrict__ is_end, int* __restrict__ lengths,
    int* __restrict__ out, unsigned key0, unsigned key1, int t, int last)
{
  __shared__ float hrow[HIDN];
  const int n = blockIdx.x;
  const int lane = threadIdx.x;
  {
    const float4* src = reinterpret_cast<const float4*>(h1 + (size_t)n * HIDN);
    float4* dst = reinterpret_cast<float4*>(hrow);
    dst[lane] = src[lane];
    dst[lane + 64] = src[lane + 64];
  }
  __syncthreads();
  const int v = lane & 31, half = lane >> 5;
  const float* w  = W_out + (size_t)v * HIDN + half * 256;
  const float* hh = hrow + half * 256;
  float dot = 0.f;
#pragma unroll
  for (int k = 0; k < 256; k += 4) {
    float4 wv = *reinterpret_cast<const float4*>(w + k);
    float4 hv = *reinterpret_cast<const float4*>(hh + k);
    dot = fmaf(wv.x, hv.x, dot);
    dot = fmaf(wv.y, hv.y, dot);
    dot = fmaf(wv.z, hv.z, dot);
    dot = fmaf(wv.w, hv.w, dot);
  }
  dot += __shfl_xor(dot, 32);
  const float logit = dot + b_out[v];

  const unsigned iflat = (unsigned)(n * 32 + v);
  unsigned r0, r1, bits;
#if RNG_VARIANT == 1
  tf2x32(key0, key1, 0u, iflat, r0, r1);
  bits = r0 ^ r1;
#elif RNG_VARIANT == 2
  if (iflat < 65536u) { tf2x32(key0, key1, iflat, iflat + 65536u, r0, r1); bits = r0; }
  else                { tf2x32(key0, key1, iflat - 65536u, iflat, r0, r1); bits = r1; }
#else
  tf2x32(key0, key1, 0u, iflat, r0, r1);
  bits = r1;
#endif
  // uniform in [tiny, 1): f = bitcast((bits>>9)|0x3f800000) - 1; u = max(f, tiny)
  float f = __uint_as_float((bits >> 9) | 0x3f800000u) - 1.0f;
  float u = fmaxf(f, 1.1754943508222875e-38f);
  // gumbel with fp32 intermediate rounding, logs at double precision (~correctly rounded)
  float t1 = -(float)log((double)u);
  float g  = -(float)log((double)t1);
  float s = g + logit;

  float bs = s; int bi = v;
#pragma unroll
  for (int off = 16; off >= 1; off >>= 1) {
    float os = __shfl_xor(bs, off);
    int   oi = __shfl_xor(bi, off);
    if (os > bs || (os == bs && oi < bi)) { bs = os; bi = oi; }
  }
  if (lane == 0) {
    const int oe  = is_end[n];
    const int cur = oe ? PAD_TOK : bi;
    const int len = lengths[n] + (oe ? 0 : 1);
    lengths[n] = len;
    is_end[n] = (oe || (cur == EOS_TOK)) ? 1 : 0;
    tok[n] = cur;
    out[(size_t)n * (TSTEPS + 1) + t + 1] = cur;
    if (last) out[(size_t)NROWS * (TSTEPS + 1) + n] = len + 1;
  }
}

// ---------------- host ----------------
extern "C" void kernel_launch(void* const* d_in, const int* in_sizes, int n_in,
                              void* d_out, int out_size, void* d_ws, size_t ws_size,
                              hipStream_t stream)
{
  const int*   prevs = (const int*)d_in[0];
  const float* emb   = (const float*)d_in[1];
  const float* W_ih0 = (const float*)d_in[2];
  const float* W_hh0 = (const float*)d_in[3];
  const float* b_ih0 = (const float*)d_in[4];
  const float* b_hh0 = (const float*)d_in[5];
  const float* W_ih1 = (const float*)d_in[6];
  const float* W_hh1 = (const float*)d_in[7];
  const float* b_ih1 = (const float*)d_in[8];
  const float* b_hh1 = (const float*)d_in[9];
  const float* W_out = (const float*)d_in[10];
  const float* b_out = (const float*)d_in[11];

  float* h0    = (float*)d_ws;                           // 4096x512
  float* c0    = h0 + (size_t)NROWS * HIDN;
  float* h1    = c0 + (size_t)NROWS * HIDN;
  float* c1    = h1 + (size_t)NROWS * HIDN;
  float* gates = c1 + (size_t)NROWS * HIDN;              // 4096x2048
  float* EW0   = gates + (size_t)NROWS * G4;             // 32x2048
  float* bias1 = EW0 + (size_t)VOC * G4;                 // 2048
  int* tok     = (int*)(bias1 + G4);
  int* is_end  = tok + NROWS;
  int* lengths = is_end + NROWS;
  int* outp    = (int*)d_out;

  hipMemsetAsync(h0, 0, (size_t)4 * NROWS * HIDN * sizeof(float), stream);
  init_state<<<NROWS / 256, 256, 0, stream>>>(prevs, tok, is_end, lengths, outp);
  build_ew0<<<VOC * G4 / 256, 256, 0, stream>>>(emb, W_ih0, b_ih0, b_hh0, EW0);
  add_bias<<<G4 / 256, 256, 0, stream>>>(b_ih1, b_hh1, bias1);

  // host-side key schedule: keys = jax.random.split(jax.random.key(7), 64)
  unsigned keys[TSTEPS][2];
#if RNG_VARIANT == 2
  {
    unsigned outv[2 * TSTEPS];
    for (int j = 0; j < TSTEPS; ++j) {
      unsigned o0, o1;
      tf2x32(0u, 7u, (unsigned)j, (unsigned)(j + TSTEPS), o0, o1);
      outv[j] = o0; outv[j + TSTEPS] = o1;
    }
    for (int t = 0; t < TSTEPS; ++t) { keys[t][0] = outv[2 * t]; keys[t][1] = outv[2 * t + 1]; }
  }
#else
  for (int t = 0; t < TSTEPS; ++t) {
    unsigned o0, o1;
    tf2x32(0u, 7u, 0u, (unsigned)t, o0, o1);
    keys[t][0] = o0; keys[t][1] = o1;
  }
#endif

  dim3 ggrid(G4 / BN, NROWS / BM);  // (16, 32)
  for (int t = 0; t < TSTEPS; ++t) {
    lstm_gemm<<<ggrid, 256, 0, stream>>>(h0, W_hh0, nullptr, nullptr, 1, gates);
    lstm_act<<<dim3(NROWS, 2), 256, 0, stream>>>(gates, EW0, tok, h0, c0);
    lstm_gemm<<<ggrid, 256, 0, stream>>>(h0, W_ih1, h1, W_hh1, 2, gates);
    lstm_act<<<dim3(NROWS, 2), 256, 0, stream>>>(gates, bias1, nullptr, h1, c1);
    sample_step<<<NROWS, 64, 0, stream>>>(h1, W_out, b_out, tok, is_end, lengths, outp,
                                          keys[t][0], keys[t][1], t, t == TSTEPS - 1);
  }
}